// Round 1
// baseline (108.140 us; speedup 1.0000x reference)
//
#include <hip/hip_runtime.h>
#include <hip/hip_bf16.h>

#define BN 4096
#define DD 128
#define MARGIN_F 1.0f

typedef __attribute__((ext_vector_type(8))) short bf16x8;
typedef __attribute__((ext_vector_type(4))) float f32x4;

__device__ __forceinline__ unsigned short f2bf(float f) {
    __hip_bfloat16 h = __float2bfloat16(f);
    return *reinterpret_cast<unsigned short*>(&h);
}

// Kernel 1: fp32 -> bf16 convert, row squared norms, zero accumulators.
// One wave per row; thread t handles elements 2t, 2t+1.
__global__ __launch_bounds__(64) void prep_kernel(
    const float* __restrict__ score,
    unsigned short* __restrict__ sbf,
    float* __restrict__ mag,
    float* __restrict__ neg,
    float* __restrict__ scalars)
{
    const int row = blockIdx.x;
    const int t = threadIdx.x;
    float2 v = *reinterpret_cast<const float2*>(score + (size_t)row * DD + t * 2);
    ushort2 w;
    w.x = f2bf(v.x);
    w.y = f2bf(v.y);
    *reinterpret_cast<ushort2*>(sbf + (size_t)row * DD + t * 2) = w;
    float s = v.x * v.x + v.y * v.y;
    #pragma unroll
    for (int o = 32; o > 0; o >>= 1) s += __shfl_down(s, o);
    if (t == 0) {
        mag[row] = s;
        neg[row] = 0.0f;
        if (row == 0) { scalars[0] = 0.0f; scalars[1] = 0.0f; }
    }
}

// Kernel 2: neg_sum[i] = sum_{j: t_j != t_i} exp(margin - dist(i,j)).
// Grid (32,32); block computes a 128x128 tile of sim via MFMA.
// 4 waves in 2x2 arrangement, each wave owns a 64x64 sub-tile (4x4 frags of 16x16x32).
__global__ __launch_bounds__(256) void negsum_kernel(
    const unsigned short* __restrict__ sbf,
    const float* __restrict__ mag,
    const int* __restrict__ tgt,
    float* __restrict__ neg)
{
    const int bi = blockIdx.x, bj = blockIdx.y;
    const int wid = threadIdx.x >> 6;
    const int lane = threadIdx.x & 63;
    const int wr = wid >> 1, wc = wid & 1;
    const int i0 = bi * 128 + wr * 64;
    const int j0 = bj * 128 + wc * 64;
    const int lhi = lane >> 4, llo = lane & 15;

    f32x4 acc[4][4] = {};
    #pragma unroll
    for (int kk = 0; kk < 4; ++kk) {
        const int koff = kk * 32 + lhi * 8;
        bf16x8 a[4], b[4];
        #pragma unroll
        for (int m = 0; m < 4; ++m)
            a[m] = *reinterpret_cast<const bf16x8*>(sbf + (size_t)(i0 + m * 16 + llo) * DD + koff);
        #pragma unroll
        for (int n = 0; n < 4; ++n)
            b[n] = *reinterpret_cast<const bf16x8*>(sbf + (size_t)(j0 + n * 16 + llo) * DD + koff);
        #pragma unroll
        for (int m = 0; m < 4; ++m)
            #pragma unroll
            for (int n = 0; n < 4; ++n)
                acc[m][n] = __builtin_amdgcn_mfma_f32_16x16x32_bf16(a[m], b[n], acc[m][n], 0, 0, 0);
    }

    // Per-lane column (j) metadata: j = j0 + n*16 + llo
    float magj[4]; int tj[4];
    #pragma unroll
    for (int n = 0; n < 4; ++n) {
        const int j = j0 + n * 16 + llo;
        magj[n] = mag[j];
        tj[n] = tgt[j];
    }

    // C/D layout: col = lane&15 (j), row = (lane>>4)*4 + r (i)
    #pragma unroll
    for (int m = 0; m < 4; ++m) {
        const int ibase = i0 + m * 16 + lhi * 4;
        f32x4 magi = *reinterpret_cast<const f32x4*>(mag + ibase);
        int4 ti4 = *reinterpret_cast<const int4*>(tgt + ibase);
        const int* tip = &ti4.x;
        #pragma unroll
        for (int r = 0; r < 4; ++r) {
            const int ti = tip[r];
            float s = 0.0f;
            #pragma unroll
            for (int n = 0; n < 4; ++n) {
                float d2 = magi[r] + magj[n] - 2.0f * acc[m][n][r];
                d2 = fmaxf(d2, 0.0f);
                float dist = sqrtf(d2);
                s += (ti != tj[n]) ? __expf(MARGIN_F - dist) : 0.0f;
            }
            // reduce across the 16 lanes (llo) that share this row
            #pragma unroll
            for (int o = 1; o < 16; o <<= 1) s += __shfl_xor(s, o);
            if (llo == 0) atomicAdd(&neg[ibase + r], s);
        }
    }
}

// Kernel 3: loss over same-class pairs i<j.
// Upper-triangle tile blocks only; same MFMA structure as negsum.
__global__ __launch_bounds__(256) void loss_kernel(
    const unsigned short* __restrict__ sbf,
    const float* __restrict__ mag,
    const int* __restrict__ tgt,
    const float* __restrict__ neg,
    float* __restrict__ scalars)
{
    const int bi = blockIdx.x, bj = blockIdx.y;
    if (bj < bi) return;   // whole tile strictly below diagonal: no i<j pairs

    const int wid = threadIdx.x >> 6;
    const int lane = threadIdx.x & 63;
    const int wr = wid >> 1, wc = wid & 1;
    const int i0 = bi * 128 + wr * 64;
    const int j0 = bj * 128 + wc * 64;
    const int lhi = lane >> 4, llo = lane & 15;

    f32x4 acc[4][4] = {};
    #pragma unroll
    for (int kk = 0; kk < 4; ++kk) {
        const int koff = kk * 32 + lhi * 8;
        bf16x8 a[4], b[4];
        #pragma unroll
        for (int m = 0; m < 4; ++m)
            a[m] = *reinterpret_cast<const bf16x8*>(sbf + (size_t)(i0 + m * 16 + llo) * DD + koff);
        #pragma unroll
        for (int n = 0; n < 4; ++n)
            b[n] = *reinterpret_cast<const bf16x8*>(sbf + (size_t)(j0 + n * 16 + llo) * DD + koff);
        #pragma unroll
        for (int m = 0; m < 4; ++m)
            #pragma unroll
            for (int n = 0; n < 4; ++n)
                acc[m][n] = __builtin_amdgcn_mfma_f32_16x16x32_bf16(a[m], b[n], acc[m][n], 0, 0, 0);
    }

    float magj[4], nsj[4]; int tj[4], jv[4];
    #pragma unroll
    for (int n = 0; n < 4; ++n) {
        const int j = j0 + n * 16 + llo;
        jv[n] = j;
        magj[n] = mag[j];
        tj[n] = tgt[j];
        nsj[n] = neg[j];
    }

    float lsum = 0.0f, lcnt = 0.0f;
    #pragma unroll
    for (int m = 0; m < 4; ++m) {
        const int ibase = i0 + m * 16 + lhi * 4;
        f32x4 magi = *reinterpret_cast<const f32x4*>(mag + ibase);
        f32x4 nsi  = *reinterpret_cast<const f32x4*>(neg + ibase);
        int4 ti4 = *reinterpret_cast<const int4*>(tgt + ibase);
        const int* tip = &ti4.x;
        #pragma unroll
        for (int r = 0; r < 4; ++r) {
            const int i = ibase + r;
            const int ti = tip[r];
            #pragma unroll
            for (int n = 0; n < 4; ++n) {
                if (ti == tj[n] && jv[n] > i) {
                    float d2 = magi[r] + magj[n] - 2.0f * acc[m][n][r];
                    d2 = fmaxf(d2, 0.0f);
                    float dist = sqrtf(d2);
                    float ln = __logf(nsi[r] + nsj[n]);
                    float u = fmaxf(ln + dist, 0.0f);
                    lsum += u * u;
                    lcnt += 1.0f;
                }
            }
        }
    }

    // full-wave reduce (64 lanes)
    #pragma unroll
    for (int o = 32; o > 0; o >>= 1) {
        lsum += __shfl_xor(lsum, o);
        lcnt += __shfl_xor(lcnt, o);
    }
    if (lane == 0) {
        atomicAdd(&scalars[0], lsum);
        atomicAdd(&scalars[1], lcnt);
    }
}

__global__ void finalize_kernel(const float* __restrict__ scalars,
                                float* __restrict__ out)
{
    const float c = fmaxf(scalars[1], 1.0f);
    out[0] = scalars[0] / (2.0f * c);
}

extern "C" void kernel_launch(void* const* d_in, const int* in_sizes, int n_in,
                              void* d_out, int out_size, void* d_ws, size_t ws_size,
                              hipStream_t stream) {
    const float* score = (const float*)d_in[0];
    const int* tgt = (const int*)d_in[1];
    float* out = (float*)d_out;

    char* ws = (char*)d_ws;
    unsigned short* sbf = (unsigned short*)ws;                       // 4096*128*2 = 1 MB
    float* mag = (float*)(ws + (size_t)BN * DD * 2);                 // 16 KB
    float* neg = mag + BN;                                           // 16 KB
    float* scalars = neg + BN;                                       // [0]=loss_sum, [1]=pos_count

    prep_kernel<<<BN, 64, 0, stream>>>(score, sbf, mag, neg, scalars);

    dim3 grid(32, 32);
    negsum_kernel<<<grid, 256, 0, stream>>>(sbf, mag, tgt, neg);
    loss_kernel<<<grid, 256, 0, stream>>>(sbf, mag, tgt, neg, scalars);
    finalize_kernel<<<1, 1, 0, stream>>>(scalars, out);
}

// Round 2
// 66.003 us; speedup vs baseline: 1.6384x; 1.6384x over previous
//
#include <hip/hip_runtime.h>
#include <hip/hip_bf16.h>

#define BN 4096
#define DD 128
#define MARGIN_F 1.0f

typedef __attribute__((ext_vector_type(8))) short bf16x8;
typedef __attribute__((ext_vector_type(4))) float f32x4;

__device__ __forceinline__ unsigned short f2bf(float f) {
    __hip_bfloat16 h = __float2bfloat16(f);
    return *reinterpret_cast<unsigned short*>(&h);
}

// Kernel 1: fp32 -> bf16 convert, row squared norms, zero neg accumulator.
__global__ __launch_bounds__(64) void prep_kernel(
    const float* __restrict__ score,
    unsigned short* __restrict__ sbf,
    float* __restrict__ mag,
    float* __restrict__ neg)
{
    const int row = blockIdx.x;
    const int t = threadIdx.x;
    float2 v = *reinterpret_cast<const float2*>(score + (size_t)row * DD + t * 2);
    ushort2 w;
    w.x = f2bf(v.x);
    w.y = f2bf(v.y);
    *reinterpret_cast<ushort2*>(sbf + (size_t)row * DD + t * 2) = w;
    float s = v.x * v.x + v.y * v.y;
    #pragma unroll
    for (int o = 32; o > 0; o >>= 1) s += __shfl_down(s, o);
    if (t == 0) {
        mag[row] = s;
        neg[row] = 0.0f;
    }
}

// Kernel 2: neg_sum[i] = sum_{j: t_j != t_i} exp(margin - dist(i,j)).
// Grid (32,32); block computes a 128x128 tile of sim via MFMA.
// 4 waves in 2x2 arrangement, each wave owns a 64x64 sub-tile (4x4 frags of 16x16x32).
__global__ __launch_bounds__(256) void negsum_kernel(
    const unsigned short* __restrict__ sbf,
    const float* __restrict__ mag,
    const int* __restrict__ tgt,
    float* __restrict__ neg)
{
    const int bi = blockIdx.x, bj = blockIdx.y;
    const int wid = threadIdx.x >> 6;
    const int lane = threadIdx.x & 63;
    const int wr = wid >> 1, wc = wid & 1;
    const int i0 = bi * 128 + wr * 64;
    const int j0 = bj * 128 + wc * 64;
    const int lhi = lane >> 4, llo = lane & 15;

    f32x4 acc[4][4] = {};
    #pragma unroll
    for (int kk = 0; kk < 4; ++kk) {
        const int koff = kk * 32 + lhi * 8;
        bf16x8 a[4], b[4];
        #pragma unroll
        for (int m = 0; m < 4; ++m)
            a[m] = *reinterpret_cast<const bf16x8*>(sbf + (size_t)(i0 + m * 16 + llo) * DD + koff);
        #pragma unroll
        for (int n = 0; n < 4; ++n)
            b[n] = *reinterpret_cast<const bf16x8*>(sbf + (size_t)(j0 + n * 16 + llo) * DD + koff);
        #pragma unroll
        for (int m = 0; m < 4; ++m)
            #pragma unroll
            for (int n = 0; n < 4; ++n)
                acc[m][n] = __builtin_amdgcn_mfma_f32_16x16x32_bf16(a[m], b[n], acc[m][n], 0, 0, 0);
    }

    // Per-lane column (j) metadata: j = j0 + n*16 + llo
    float magj[4]; int tj[4];
    #pragma unroll
    for (int n = 0; n < 4; ++n) {
        const int j = j0 + n * 16 + llo;
        magj[n] = mag[j];
        tj[n] = tgt[j];
    }

    // C/D layout: col = lane&15 (j), row = (lane>>4)*4 + r (i)
    #pragma unroll
    for (int m = 0; m < 4; ++m) {
        const int ibase = i0 + m * 16 + lhi * 4;
        f32x4 magi = *reinterpret_cast<const f32x4*>(mag + ibase);
        int4 ti4 = *reinterpret_cast<const int4*>(tgt + ibase);
        const int* tip = &ti4.x;
        #pragma unroll
        for (int r = 0; r < 4; ++r) {
            const int ti = tip[r];
            float s = 0.0f;
            #pragma unroll
            for (int n = 0; n < 4; ++n) {
                float d2 = magi[r] + magj[n] - 2.0f * acc[m][n][r];
                d2 = fmaxf(d2, 0.0f);
                float dist = sqrtf(d2);
                s += (ti != tj[n]) ? __expf(MARGIN_F - dist) : 0.0f;
            }
            // reduce across the 16 lanes (llo) that share this row
            #pragma unroll
            for (int o = 1; o < 16; o <<= 1) s += __shfl_xor(s, o);
            if (llo == 0) atomicAdd(&neg[ibase + r], s);
        }
    }
}

// Kernel 3: loss over same-class pairs i<j.
// Upper-triangle tile blocks only; per-block non-atomic partial output.
__global__ __launch_bounds__(256) void loss_kernel(
    const unsigned short* __restrict__ sbf,
    const float* __restrict__ mag,
    const int* __restrict__ tgt,
    const float* __restrict__ neg,
    float2* __restrict__ part)
{
    const int bi = blockIdx.x, bj = blockIdx.y;
    const int bid = bj * 32 + bi;
    if (bj < bi) {   // whole tile strictly below diagonal: no i<j pairs
        if (threadIdx.x == 0) part[bid] = make_float2(0.0f, 0.0f);
        return;
    }

    const int wid = threadIdx.x >> 6;
    const int lane = threadIdx.x & 63;
    const int wr = wid >> 1, wc = wid & 1;
    const int i0 = bi * 128 + wr * 64;
    const int j0 = bj * 128 + wc * 64;
    const int lhi = lane >> 4, llo = lane & 15;

    f32x4 acc[4][4] = {};
    #pragma unroll
    for (int kk = 0; kk < 4; ++kk) {
        const int koff = kk * 32 + lhi * 8;
        bf16x8 a[4], b[4];
        #pragma unroll
        for (int m = 0; m < 4; ++m)
            a[m] = *reinterpret_cast<const bf16x8*>(sbf + (size_t)(i0 + m * 16 + llo) * DD + koff);
        #pragma unroll
        for (int n = 0; n < 4; ++n)
            b[n] = *reinterpret_cast<const bf16x8*>(sbf + (size_t)(j0 + n * 16 + llo) * DD + koff);
        #pragma unroll
        for (int m = 0; m < 4; ++m)
            #pragma unroll
            for (int n = 0; n < 4; ++n)
                acc[m][n] = __builtin_amdgcn_mfma_f32_16x16x32_bf16(a[m], b[n], acc[m][n], 0, 0, 0);
    }

    float magj[4], nsj[4]; int tj[4], jv[4];
    #pragma unroll
    for (int n = 0; n < 4; ++n) {
        const int j = j0 + n * 16 + llo;
        jv[n] = j;
        magj[n] = mag[j];
        tj[n] = tgt[j];
        nsj[n] = neg[j];
    }

    float lsum = 0.0f, lcnt = 0.0f;
    #pragma unroll
    for (int m = 0; m < 4; ++m) {
        const int ibase = i0 + m * 16 + lhi * 4;
        f32x4 magi = *reinterpret_cast<const f32x4*>(mag + ibase);
        f32x4 nsi  = *reinterpret_cast<const f32x4*>(neg + ibase);
        int4 ti4 = *reinterpret_cast<const int4*>(tgt + ibase);
        const int* tip = &ti4.x;
        #pragma unroll
        for (int r = 0; r < 4; ++r) {
            const int i = ibase + r;
            const int ti = tip[r];
            #pragma unroll
            for (int n = 0; n < 4; ++n) {
                if (ti == tj[n] && jv[n] > i) {
                    float d2 = magi[r] + magj[n] - 2.0f * acc[m][n][r];
                    d2 = fmaxf(d2, 0.0f);
                    float dist = sqrtf(d2);
                    float ln = __logf(nsi[r] + nsj[n]);
                    float u = fmaxf(ln + dist, 0.0f);
                    lsum += u * u;
                    lcnt += 1.0f;
                }
            }
        }
    }

    // full-wave reduce (64 lanes)
    #pragma unroll
    for (int o = 32; o > 0; o >>= 1) {
        lsum += __shfl_xor(lsum, o);
        lcnt += __shfl_xor(lcnt, o);
    }

    // block reduce across the 4 waves via LDS, single store per block
    __shared__ float2 wpart[4];
    if (lane == 0) wpart[wid] = make_float2(lsum, lcnt);
    __syncthreads();
    if (threadIdx.x == 0) {
        float s = 0.0f, c = 0.0f;
        #pragma unroll
        for (int w = 0; w < 4; ++w) { s += wpart[w].x; c += wpart[w].y; }
        part[bid] = make_float2(s, c);
    }
}

// Kernel 4: reduce 1024 block partials, write scalar output.
__global__ __launch_bounds__(256) void finalize_kernel(
    const float2* __restrict__ part,
    float* __restrict__ out)
{
    const int t = threadIdx.x;
    float s = 0.0f, c = 0.0f;
    #pragma unroll
    for (int k = 0; k < 4; ++k) {
        float2 p = part[t + k * 256];
        s += p.x;
        c += p.y;
    }
    #pragma unroll
    for (int o = 32; o > 0; o >>= 1) {
        s += __shfl_xor(s, o);
        c += __shfl_xor(c, o);
    }
    __shared__ float2 w[4];
    const int wid = t >> 6, lane = t & 63;
    if (lane == 0) w[wid] = make_float2(s, c);
    __syncthreads();
    if (t == 0) {
        float ts = 0.0f, tc = 0.0f;
        #pragma unroll
        for (int k = 0; k < 4; ++k) { ts += w[k].x; tc += w[k].y; }
        out[0] = ts / (2.0f * fmaxf(tc, 1.0f));
    }
}

extern "C" void kernel_launch(void* const* d_in, const int* in_sizes, int n_in,
                              void* d_out, int out_size, void* d_ws, size_t ws_size,
                              hipStream_t stream) {
    const float* score = (const float*)d_in[0];
    const int* tgt = (const int*)d_in[1];
    float* out = (float*)d_out;

    char* ws = (char*)d_ws;
    unsigned short* sbf = (unsigned short*)ws;                       // 4096*128*2 = 1 MB
    float* mag = (float*)(ws + (size_t)BN * DD * 2);                 // 16 KB
    float* neg = mag + BN;                                           // 16 KB
    float2* part = (float2*)(neg + BN);                              // 1024 * 8B = 8 KB

    prep_kernel<<<BN, 64, 0, stream>>>(score, sbf, mag, neg);

    dim3 grid(32, 32);
    negsum_kernel<<<grid, 256, 0, stream>>>(sbf, mag, tgt, neg);
    loss_kernel<<<grid, 256, 0, stream>>>(sbf, mag, tgt, neg, part);
    finalize_kernel<<<1, 256, 0, stream>>>(part, out);
}

// Round 3
// 60.508 us; speedup vs baseline: 1.7872x; 1.0908x over previous
//
#include <hip/hip_runtime.h>
#include <hip/hip_bf16.h>

#define BN 4096
#define DD 128
#define NCLS 64
#define MARGIN_F 1.0f
#define NT64 64          // 4096/64 tiles per dim
#define NTRI 2080        // 64*65/2 triangle tiles

typedef __attribute__((ext_vector_type(8))) short bf16x8;
typedef __attribute__((ext_vector_type(4))) float f32x4;

__device__ __forceinline__ unsigned short f2bf(float f) {
    __hip_bfloat16 h = __float2bfloat16(f);
    return *reinterpret_cast<unsigned short*>(&h);
}

// K1: fp32 -> bf16 convert, row squared norms, zero neg; block 0 zeros bins.
__global__ __launch_bounds__(64) void prep_kernel(
    const float* __restrict__ score,
    unsigned short* __restrict__ sbf,
    float* __restrict__ mag,
    float* __restrict__ neg,
    int* __restrict__ bins)
{
    const int row = blockIdx.x;
    const int t = threadIdx.x;
    if (row == 0) bins[t] = 0;
    float2 v = *reinterpret_cast<const float2*>(score + (size_t)row * DD + t * 2);
    ushort2 w;
    w.x = f2bf(v.x);
    w.y = f2bf(v.y);
    *reinterpret_cast<ushort2*>(sbf + (size_t)row * DD + t * 2) = w;
    float s = v.x * v.x + v.y * v.y;
    #pragma unroll
    for (int o = 32; o > 0; o >>= 1) s += __shfl_down(s, o);
    if (t == 0) {
        mag[row] = s;
        neg[row] = 0.0f;
    }
}

// K2: class histogram (LDS-local then merge).
__global__ __launch_bounds__(256) void hist_kernel(
    const int* __restrict__ tgt, int* __restrict__ bins)
{
    __shared__ int h[NCLS];
    const int t = threadIdx.x;
    if (t < NCLS) h[t] = 0;
    __syncthreads();
    const int i = blockIdx.x * 256 + t;
    atomicAdd(&h[tgt[i]], 1);
    __syncthreads();
    if (t < NCLS) atomicAdd(&bins[t], h[t]);
}

// K3: exclusive prefix over 64 bins; bins becomes scatter cursor.
__global__ __launch_bounds__(64) void scan_kernel(
    int* __restrict__ bins, int* __restrict__ cls_off, int* __restrict__ cls_cnt)
{
    const int t = threadIdx.x;
    int v = bins[t];
    int inc = v;
    #pragma unroll
    for (int o = 1; o < 64; o <<= 1) {
        int u = __shfl_up(inc, o);
        if (t >= o) inc += u;
    }
    int exc = inc - v;
    cls_off[t] = exc;
    cls_cnt[t] = v;
    bins[t] = exc;
}

// K4: scatter row ids into class-sorted perm.
__global__ __launch_bounds__(256) void scatter_kernel(
    const int* __restrict__ tgt, int* __restrict__ bins, int* __restrict__ perm)
{
    const int i = blockIdx.x * 256 + threadIdx.x;
    const int pos = atomicAdd(&bins[tgt[i]], 1);
    perm[pos] = i;
}

// K5: neg_sum via symmetric triangle. One wave per 64x64 tile, 2080 tiles.
// exp(margin-dist) computed once per unordered pair; row-reduce feeds neg[i],
// col-reduce feeds neg[j] (off-diagonal tiles only).
__global__ __launch_bounds__(64) void negsum_tri_kernel(
    const unsigned short* __restrict__ sbf,
    const float* __restrict__ mag,
    const int* __restrict__ tgt,
    float* __restrict__ neg)
{
    const int idx = blockIdx.x;
    // decode triangle tile (bi <= bj) in a 64x64 tile grid
    int bi = (int)((129.0f - sqrtf(16641.0f - 8.0f * (float)idx)) * 0.5f);
    bi = max(0, min(bi, 63));
    while (bi * (129 - bi) / 2 > idx) --bi;
    while ((bi + 1) * (128 - bi) / 2 <= idx) ++bi;
    const int bj = bi + (idx - bi * (129 - bi) / 2);
    const bool diag = (bi == bj);
    const int i0 = bi * 64, j0 = bj * 64;
    const int lane = threadIdx.x;
    const int lhi = lane >> 4, llo = lane & 15;

    f32x4 acc[4][4] = {};
    #pragma unroll
    for (int kk = 0; kk < 4; ++kk) {
        const int koff = kk * 32 + lhi * 8;
        bf16x8 a[4], b[4];
        #pragma unroll
        for (int m = 0; m < 4; ++m)
            a[m] = *reinterpret_cast<const bf16x8*>(sbf + (size_t)(i0 + m * 16 + llo) * DD + koff);
        #pragma unroll
        for (int n = 0; n < 4; ++n)
            b[n] = *reinterpret_cast<const bf16x8*>(sbf + (size_t)(j0 + n * 16 + llo) * DD + koff);
        #pragma unroll
        for (int m = 0; m < 4; ++m)
            #pragma unroll
            for (int n = 0; n < 4; ++n)
                acc[m][n] = __builtin_amdgcn_mfma_f32_16x16x32_bf16(a[m], b[n], acc[m][n], 0, 0, 0);
    }

    float magj[4]; int tj[4];
    #pragma unroll
    for (int n = 0; n < 4; ++n) {
        const int j = j0 + n * 16 + llo;
        magj[n] = mag[j];
        tj[n] = tgt[j];
    }

    float cs[4] = {0.0f, 0.0f, 0.0f, 0.0f};
    // C/D layout: col = lane&15 (j), row = (lane>>4)*4 + r (i)
    #pragma unroll
    for (int m = 0; m < 4; ++m) {
        const int ibase = i0 + m * 16 + lhi * 4;
        f32x4 magi = *reinterpret_cast<const f32x4*>(mag + ibase);
        int4 ti4 = *reinterpret_cast<const int4*>(tgt + ibase);
        const int* tip = &ti4.x;
        #pragma unroll
        for (int r = 0; r < 4; ++r) {
            const int ti = tip[r];
            float s = 0.0f;
            #pragma unroll
            for (int n = 0; n < 4; ++n) {
                float d2 = magi[r] + magj[n] - 2.0f * acc[m][n][r];
                d2 = fmaxf(d2, 0.0f);
                float dist = sqrtf(d2);
                float v = (ti != tj[n]) ? __expf(MARGIN_F - dist) : 0.0f;
                s += v;
                cs[n] += v;
            }
            #pragma unroll
            for (int o = 1; o < 16; o <<= 1) s += __shfl_xor(s, o);
            if (llo == 0) atomicAdd(&neg[ibase + r], s);
        }
    }
    if (!diag) {
        #pragma unroll
        for (int n = 0; n < 4; ++n) {
            cs[n] += __shfl_xor(cs[n], 16);
            cs[n] += __shfl_xor(cs[n], 32);
        }
        if (lhi == 0) {
            #pragma unroll
            for (int n = 0; n < 4; ++n)
                atomicAdd(&neg[j0 + n * 16 + llo], cs[n]);
        }
    }
}

// K6: loss over same-class pairs via class-sorted gather. One block per class.
__global__ __launch_bounds__(256) void loss_cls_kernel(
    const unsigned short* __restrict__ sbf,
    const float* __restrict__ mag,
    const float* __restrict__ neg,
    const int* __restrict__ perm,
    const int* __restrict__ cls_off,
    const int* __restrict__ cls_cnt,
    float2* __restrict__ part)
{
    const int c = blockIdx.x;
    const int n_c = cls_cnt[c];
    const int base = cls_off[c];
    const int tid = threadIdx.x;
    const int wid = tid >> 6, lane = tid & 63;
    const int wr = wid >> 1, wc = wid & 1;
    const int p0 = wr * 64, q0 = wc * 64;
    const int lhi = lane >> 4, llo = lane & 15;

    float lsum = 0.0f, lcnt = 0.0f;
    const bool active = (n_c > 0) && (wc >= wr) && (p0 < n_c) && (q0 < n_c);
    if (active) {
        int opA[4], opB[4];
        #pragma unroll
        for (int m = 0; m < 4; ++m) {
            const int p = p0 + m * 16 + llo;
            opA[m] = perm[base + min(p, n_c - 1)];
        }
        #pragma unroll
        for (int n = 0; n < 4; ++n) {
            const int q = q0 + n * 16 + llo;
            opB[n] = perm[base + min(q, n_c - 1)];
        }
        f32x4 acc[4][4] = {};
        #pragma unroll
        for (int kk = 0; kk < 4; ++kk) {
            const int koff = kk * 32 + lhi * 8;
            bf16x8 a[4], b[4];
            #pragma unroll
            for (int m = 0; m < 4; ++m)
                a[m] = *reinterpret_cast<const bf16x8*>(sbf + (size_t)opA[m] * DD + koff);
            #pragma unroll
            for (int n = 0; n < 4; ++n)
                b[n] = *reinterpret_cast<const bf16x8*>(sbf + (size_t)opB[n] * DD + koff);
            #pragma unroll
            for (int m = 0; m < 4; ++m)
                #pragma unroll
                for (int n = 0; n < 4; ++n)
                    acc[m][n] = __builtin_amdgcn_mfma_f32_16x16x32_bf16(a[m], b[n], acc[m][n], 0, 0, 0);
        }

        float magjv[4], nsj[4]; int qv[4];
        #pragma unroll
        for (int n = 0; n < 4; ++n) {
            qv[n] = q0 + n * 16 + llo;
            magjv[n] = mag[opB[n]];
            nsj[n] = neg[opB[n]];
        }

        #pragma unroll
        for (int m = 0; m < 4; ++m) {
            #pragma unroll
            for (int r = 0; r < 4; ++r) {
                const int p = p0 + m * 16 + lhi * 4 + r;
                const bool pv = (p < n_c);
                const int io = perm[base + min(p, n_c - 1)];
                const float magiv = mag[io];
                const float nsi = neg[io];
                #pragma unroll
                for (int n = 0; n < 4; ++n) {
                    if (pv && qv[n] > p && qv[n] < n_c) {
                        float d2 = magiv + magjv[n] - 2.0f * acc[m][n][r];
                        d2 = fmaxf(d2, 0.0f);
                        float dist = sqrtf(d2);
                        float ln = __logf(nsi + nsj[n]);
                        float u = fmaxf(ln + dist, 0.0f);
                        lsum += u * u;
                        lcnt += 1.0f;
                    }
                }
            }
        }
    }

    #pragma unroll
    for (int o = 32; o > 0; o >>= 1) {
        lsum += __shfl_xor(lsum, o);
        lcnt += __shfl_xor(lcnt, o);
    }
    __shared__ float2 wpart[4];
    if (lane == 0) wpart[wid] = make_float2(lsum, lcnt);
    __syncthreads();
    if (tid == 0) {
        float s = 0.0f, cc = 0.0f;
        #pragma unroll
        for (int w = 0; w < 4; ++w) { s += wpart[w].x; cc += wpart[w].y; }
        part[c] = make_float2(s, cc);
    }
}

// K7: reduce 64 class partials -> scalar.
__global__ __launch_bounds__(64) void finalize_kernel(
    const float2* __restrict__ part, float* __restrict__ out)
{
    const int t = threadIdx.x;
    float2 p = part[t];
    float s = p.x, c = p.y;
    #pragma unroll
    for (int o = 32; o > 0; o >>= 1) {
        s += __shfl_xor(s, o);
        c += __shfl_xor(c, o);
    }
    if (t == 0) out[0] = s / (2.0f * fmaxf(c, 1.0f));
}

extern "C" void kernel_launch(void* const* d_in, const int* in_sizes, int n_in,
                              void* d_out, int out_size, void* d_ws, size_t ws_size,
                              hipStream_t stream) {
    const float* score = (const float*)d_in[0];
    const int* tgt = (const int*)d_in[1];
    float* out = (float*)d_out;

    char* ws = (char*)d_ws;
    unsigned short* sbf = (unsigned short*)ws;               // 1 MB
    float* mag = (float*)(ws + (size_t)BN * DD * 2);         // 16 KB
    float* neg = mag + BN;                                   // 16 KB
    int* perm = (int*)(neg + BN);                            // 16 KB
    int* bins = perm + BN;                                   // 256 B
    int* cls_off = bins + NCLS;                              // 256 B
    int* cls_cnt = cls_off + NCLS;                           // 256 B
    float2* part = (float2*)(cls_cnt + NCLS);                // 512 B (8B-aligned)

    prep_kernel<<<BN, 64, 0, stream>>>(score, sbf, mag, neg, bins);
    hist_kernel<<<BN / 256, 256, 0, stream>>>(tgt, bins);
    scan_kernel<<<1, 64, 0, stream>>>(bins, cls_off, cls_cnt);
    scatter_kernel<<<BN / 256, 256, 0, stream>>>(tgt, bins, perm);
    negsum_tri_kernel<<<NTRI, 64, 0, stream>>>(sbf, mag, tgt, neg);
    loss_cls_kernel<<<NCLS, 256, 0, stream>>>(sbf, mag, neg, perm, cls_off, cls_cnt, part);
    finalize_kernel<<<1, 64, 0, stream>>>(part, out);
}